// Round 5
// baseline (1195.491 us; speedup 1.0000x reference)
//
#include <hip/hip_runtime.h>
#include <hip/hip_bf16.h>

#define DIMN  256
#define NOBJ  16384
#define NPAIR 131072
#define NINC  (2 * NPAIR)

typedef float  floatx4 __attribute__((ext_vector_type(4)));
typedef __bf16 bf16x8  __attribute__((ext_vector_type(8)));

static __device__ __forceinline__ unsigned f2bf(float f) {
  unsigned u = __builtin_bit_cast(unsigned, f);
  u += 0x7FFFu + ((u >> 16) & 1u);          // round-to-nearest-even
  return u >> 16;
}
static __device__ __forceinline__ float sigmoidf_(float x) {
  return 1.0f / (1.0f + __expf(-x));
}
static __device__ __forceinline__ float tanhf_(float x) {
  return 1.0f - 2.0f / (1.0f + __expf(2.0f * x));
}
static __device__ __forceinline__ float dot4(float4 a, float4 b) {
  return a.x*b.x + a.y*b.y + a.z*b.z + a.w*b.w;
}
static __device__ __forceinline__ float4 relu4(float4 a) {
  float4 r; r.x = fmaxf(a.x,0.f); r.y = fmaxf(a.y,0.f);
  r.z = fmaxf(a.z,0.f); r.w = fmaxf(a.w,0.f); return r;
}
static __device__ __forceinline__ floatx4 mfma16(bf16x8 a, bf16x8 b, floatx4 c) {
  return __builtin_amdgcn_mfma_f32_16x16x32_bf16(a, b, c, 0, 0, 0);
}
// fp32x8 -> bf16x8 via scalar casts; compiler emits v_cvt_pk_bf16_f32 pairs
// (RNE, same result as manual f2bf, ~4x fewer VALU ops).
static __device__ __forceinline__ bf16x8 cvt8(float4 u, float4 v) {
  bf16x8 r;
  r[0] = (__bf16)u.x; r[1] = (__bf16)u.y; r[2] = (__bf16)u.z; r[3] = (__bf16)u.w;
  r[4] = (__bf16)v.x; r[5] = (__bf16)v.y; r[6] = (__bf16)v.z; r[7] = (__bf16)v.w;
  return r;
}

// ---------------------------------------------------------------------------
// weight fp32 -> bf16, repacked into per-col-tile MFMA fragment order:
//   frag index i = ((ct*6 + s)*8 + kc)*64 + lane      (49152 frags of 16 B)
//   ct = col-tile of 16, s = stream (0..2 Wih r/z/n, 3..5 Whh r/z/n),
//   kc = K-chunk of 32, lane = (quad,l16): col = ct*16+l16, k0 = kc*32+quad*8.
__global__ __launch_bounds__(256) void conv_w(const float* __restrict__ wih,
                                              const float* __restrict__ whh,
                                              unsigned short* __restrict__ out) {
  const int i    = blockIdx.x * 256 + threadIdx.x;   // 0..49151
  const int lane = i & 63;
  const int kc   = (i >> 6) & 7;
  const int sct  = i >> 9;           // ct*6 + s
  const int s    = sct % 6;
  const int ct   = sct / 6;
  const int col  = ct * 16 + (lane & 15);
  const int k0   = kc * 32 + (lane >> 4) * 8;
  const float* src = (s < 3) ? (wih + ((size_t)(s * 256 + col)) * 256 + k0)
                             : (whh + ((size_t)((s - 3) * 256 + col)) * 256 + k0);
  float4 a = ((const float4*)src)[0];
  float4 b = ((const float4*)src)[1];
  uint4 pk;
  pk.x = f2bf(a.x) | (f2bf(a.y) << 16);
  pk.y = f2bf(a.z) | (f2bf(a.w) << 16);
  pk.z = f2bf(b.x) | (f2bf(b.y) << 16);
  pk.w = f2bf(b.z) | (f2bf(b.w) << 16);
  *(uint4*)(out + (size_t)i * 8) = pk;
}

// ---------------------------------------------------------------------------
// CSR build: histogram -> scan -> scatter. Incidence i (0..NINC): object
// pairs[i], pair p=i>>1, side i&1 (0=subj uses g_s, 1=obj uses g_o).
__global__ __launch_bounds__(256) void hist_kernel(const int* __restrict__ pairs,
                                                   int* __restrict__ cnt) {
  int i = blockIdx.x * 256 + threadIdx.x;
  atomicAdd(&cnt[pairs[i]], 1);
}

__global__ __launch_bounds__(1024) void scan_kernel(const int* __restrict__ cnt,
                                                    int* __restrict__ row_start,
                                                    int* __restrict__ cursor) {
  __shared__ int sums[1024];
  const int t = threadIdx.x;
  const int base = t * 16;
  int local[16];
  int s = 0;
  #pragma unroll
  for (int i = 0; i < 16; i++) { local[i] = s; s += cnt[base + i]; }
  sums[t] = s;
  __syncthreads();
  for (int off = 1; off < 1024; off <<= 1) {
    int v = (t >= off) ? sums[t - off] : 0;
    __syncthreads();
    sums[t] += v;
    __syncthreads();
  }
  const int prefix = (t == 0) ? 0 : sums[t - 1];
  #pragma unroll
  for (int i = 0; i < 16; i++) {
    int v = prefix + local[i];
    row_start[base + i] = v;
    cursor[base + i] = v;
  }
  if (t == 1023) row_start[16384] = sums[1023];
}

__global__ __launch_bounds__(256) void scatter_kernel(const int* __restrict__ pairs,
                                                      int* __restrict__ cursor,
                                                      int* __restrict__ entries) {
  int i = blockIdx.x * 256 + threadIdx.x;
  int pos = atomicAdd(&cursor[pairs[i]], 1);
  entries[pos] = i;
}

// ---------------------------------------------------------------------------
// Gate kernel: one wave per pair. Computes 4 gate scalars; writes
// xg = m_s2p + m_o2p (input to pred-GRU) and gbuf[2p]=g_s, gbuf[2p+1]=g_o.
__global__ __launch_bounds__(256) void gate_kernel(
    const float* __restrict__ xobj, const float* __restrict__ xpred,
    const int* __restrict__ pairs,
    const float* __restrict__ w_e2v, const float* __restrict__ b_e2v,
    const float* __restrict__ w_v2e, const float* __restrict__ b_v2e,
    float* __restrict__ gbuf, float* __restrict__ xg)
{
  const int wave = threadIdx.x >> 6;
  const int lane = threadIdx.x & 63;
  const int p = blockIdx.x * 4 + wave;
  const int s = pairs[2*p], o = pairs[2*p+1];

  float4 vp = ((const float4*)(xpred + (size_t)p*DIMN))[lane];
  float4 vs = ((const float4*)(xobj  + (size_t)s*DIMN))[lane];
  float4 vo = ((const float4*)(xobj  + (size_t)o*DIMN))[lane];
  float4 we0 = ((const float4*)w_e2v)[lane];
  float4 we1 = ((const float4*)w_e2v)[64 + lane];
  float4 wv0 = ((const float4*)w_v2e)[lane];
  float4 wv1 = ((const float4*)w_v2e)[64 + lane];

  float4 rp = relu4(vp), rs = relu4(vs), ro = relu4(vo);
  float t0 = dot4(rs, we0);
  float t1 = dot4(ro, we0);
  float t2 = dot4(rp, we1);
  float t3 = dot4(rp, wv0);
  float t4 = dot4(rs, wv1);
  float t5 = dot4(ro, wv1);
  #pragma unroll
  for (int off = 32; off >= 1; off >>= 1) {
    t0 += __shfl_xor(t0, off); t1 += __shfl_xor(t1, off);
    t2 += __shfl_xor(t2, off); t3 += __shfl_xor(t3, off);
    t4 += __shfl_xor(t4, off); t5 += __shfl_xor(t5, off);
  }
  const float be = b_e2v[0], bv = b_v2e[0];
  const float g_s  = sigmoidf_(t0 + t2 + be);
  const float g_o  = sigmoidf_(t1 + t2 + be);
  const float g_sp = sigmoidf_(t3 + t4 + bv);
  const float g_op = sigmoidf_(t3 + t5 + bv);

  float4 xgv;
  xgv.x = vs.x*g_sp + vo.x*g_op; xgv.y = vs.y*g_sp + vo.y*g_op;
  xgv.z = vs.z*g_sp + vo.z*g_op; xgv.w = vs.w*g_sp + vo.w*g_op;
  ((float4*)(xg + (size_t)p*DIMN))[lane] = xgv;

  if (lane == 0) { gbuf[2*p] = g_s; gbuf[2*p+1] = g_o; }
}

// ---------------------------------------------------------------------------
// Gather segment-sum: one wave per object.
__global__ __launch_bounds__(256) void gather_kernel(
    const float* __restrict__ xpred, const float* __restrict__ gbuf,
    const int* __restrict__ row_start, const int* __restrict__ entries,
    float* __restrict__ msg)
{
  const int wave = threadIdx.x >> 6;
  const int lane = threadIdx.x & 63;
  const int obj = blockIdx.x * 4 + wave;
  const int s0 = row_start[obj], s1 = row_start[obj + 1];

  float4 acc = {0.f, 0.f, 0.f, 0.f};
  int inc = (s0 < s1) ? entries[s0] : 0;
  for (int e = s0; e < s1; e++) {
    int ninc = (e + 1 < s1) ? entries[e + 1] : 0;   // prefetch next index
    float g = gbuf[inc];
    float4 v = ((const float4*)(xpred + (size_t)(inc >> 1) * DIMN))[lane];
    acc.x += g * v.x; acc.y += g * v.y; acc.z += g * v.z; acc.w += g * v.w;
    inc = ninc;
  }
  ((float4*)(msg + (size_t)obj * DIMN))[lane] = acc;
}

// ---------------------------------------------------------------------------
// Fused GRU v6. Block = **32 rows** x 256 cols, 8 waves (512 thr); wave w
// owns cols [32w, 32w+32) as two col-tiles processed serially (B liveness
// 6 frags). Register budget BY DESIGN <= 128/wave: acc 64 + A 16 + B 24 +
// addr ~15 ~= 120, enforced with __launch_bounds__(512,4) -> 4 waves/SIMD
// -> **2 independent blocks/CU** (LDS 32 KB/block), so one block's K-loop
// overlaps another block's HBM staging. (v4/v5 were 1 block/CU with fully
// serialized stage->compute->epilogue phases; v5's 244-reg layout gave only
// 8 waves/CU.) Staging converts via cvt_pk casts (not manual bit-ops).
__global__ __launch_bounds__(512, 4) void gru_kernel(
    const float* __restrict__ X, const float* __restrict__ H,
    const unsigned short* __restrict__ Wpk,
    const float* __restrict__ b_ih, const float* __restrict__ b_hh,
    float* __restrict__ OUT)
{
  __shared__ unsigned short Xs[32 * 256];
  __shared__ unsigned short Hs[32 * 256];

  const int tid  = threadIdx.x;
  const int lane = tid & 63;
  const int wave = tid >> 6;          // 0..7 -> col pair (32 cols)
  const int quad = lane >> 4;
  const int l16  = lane & 15;
  const int rowBase = blockIdx.x * 32;
  const int col0 = wave * 32 + l16;
  const int col1 = col0 + 16;

  // fragment bases for the wave's two col-tiles (ushort offsets)
  const unsigned short* wb0 = Wpk + (size_t)(wave * 2)     * 24576 + lane * 8;
  const unsigned short* wb1 = Wpk + (size_t)(wave * 2 + 1) * 24576 + lane * 8;

  // ---- stage A: 32 rows x 256 fp32 -> bf16 LDS (XOR-swizzled 16B chunks)
  {
    const int r  = tid >> 4;          // row 0..31
    const int c0 = tid & 15;          // chunk base; 16 threads per row
    const float* xr = X + (size_t)(rowBase + r) * DIMN;
    const float* hr = H + (size_t)(rowBase + r) * DIMN;
    #pragma unroll
    for (int half = 0; half < 2; half++) {
      const int c  = c0 + half * 16;            // 16B chunk 0..31
      const int sw = (c ^ (r & 7)) * 8;         // swizzled ushort offset
      float4 u = ((const float4*)xr)[2*c];
      float4 v = ((const float4*)xr)[2*c + 1];
      *(bf16x8*)(Xs + r * 256 + sw) = cvt8(u, v);
      u = ((const float4*)hr)[2*c];
      v = ((const float4*)hr)[2*c + 1];
      *(bf16x8*)(Hs + r * 256 + sw) = cvt8(u, v);
    }
  }
  __syncthreads();

  floatx4 ar0[2], az0[2], an0[2], ah0[2];
  floatx4 ar1[2], az1[2], an1[2], ah1[2];
  #pragma unroll
  for (int mt = 0; mt < 2; mt++) {
    ar0[mt] = (floatx4){0,0,0,0}; az0[mt] = (floatx4){0,0,0,0};
    an0[mt] = (floatx4){0,0,0,0}; ah0[mt] = (floatx4){0,0,0,0};
    ar1[mt] = (floatx4){0,0,0,0}; az1[mt] = (floatx4){0,0,0,0};
    an1[mt] = (floatx4){0,0,0,0}; ah1[mt] = (floatx4){0,0,0,0};
  }

  #pragma unroll
  for (int kc = 0; kc < 8; kc++) {
    // A fragments for both M-tiles (shared by both col-tiles)
    const int sw  = ((kc * 4 + quad) ^ (l16 & 7)) * 8;   // row&7 == l16&7
    const int ao0 = l16 * 256 + sw;
    const int ao1 = (16 + l16) * 256 + sw;
    bf16x8 aX0 = *(const bf16x8*)(Xs + ao0);
    bf16x8 aH0 = *(const bf16x8*)(Hs + ao0);
    bf16x8 aX1 = *(const bf16x8*)(Xs + ao1);
    bf16x8 aH1 = *(const bf16x8*)(Hs + ao1);

    {   // col-tile 0: 6 B frags, 12 MFMA
      const unsigned short* wk = wb0 + kc * 512;
      bf16x8 bri = *(const bf16x8*)(wk);
      bf16x8 bzi = *(const bf16x8*)(wk +  4096);
      bf16x8 bni = *(const bf16x8*)(wk +  8192);
      bf16x8 brh = *(const bf16x8*)(wk + 12288);
      bf16x8 bzh = *(const bf16x8*)(wk + 16384);
      bf16x8 bnh = *(const bf16x8*)(wk + 20480);
      ar0[0] = mfma16(aX0, bri, ar0[0]);  ar0[1] = mfma16(aX1, bri, ar0[1]);
      ar0[0] = mfma16(aH0, brh, ar0[0]);  ar0[1] = mfma16(aH1, brh, ar0[1]);
      az0[0] = mfma16(aX0, bzi, az0[0]);  az0[1] = mfma16(aX1, bzi, az0[1]);
      az0[0] = mfma16(aH0, bzh, az0[0]);  az0[1] = mfma16(aH1, bzh, az0[1]);
      an0[0] = mfma16(aX0, bni, an0[0]);  an0[1] = mfma16(aX1, bni, an0[1]);
      ah0[0] = mfma16(aH0, bnh, ah0[0]);  ah0[1] = mfma16(aH1, bnh, ah0[1]);
    }
    {   // col-tile 1
      const unsigned short* wk = wb1 + kc * 512;
      bf16x8 bri = *(const bf16x8*)(wk);
      bf16x8 bzi = *(const bf16x8*)(wk +  4096);
      bf16x8 bni = *(const bf16x8*)(wk +  8192);
      bf16x8 brh = *(const bf16x8*)(wk + 12288);
      bf16x8 bzh = *(const bf16x8*)(wk + 16384);
      bf16x8 bnh = *(const bf16x8*)(wk + 20480);
      ar1[0] = mfma16(aX0, bri, ar1[0]);  ar1[1] = mfma16(aX1, bri, ar1[1]);
      ar1[0] = mfma16(aH0, brh, ar1[0]);  ar1[1] = mfma16(aH1, brh, ar1[1]);
      az1[0] = mfma16(aX0, bzi, az1[0]);  az1[1] = mfma16(aX1, bzi, az1[1]);
      az1[0] = mfma16(aH0, bzh, az1[0]);  az1[1] = mfma16(aH1, bzh, az1[1]);
      an1[0] = mfma16(aX0, bni, an1[0]);  an1[1] = mfma16(aX1, bni, an1[1]);
      ah1[0] = mfma16(aH0, bnh, ah1[0]);  ah1[1] = mfma16(aH1, bnh, ah1[1]);
    }
  }

  // epilogue: C layout col=lane&15, row=quad*4+v (m89-verified)
  {
    const float br  = b_ih[col0]       + b_hh[col0];
    const float bz  = b_ih[col0 + 256] + b_hh[col0 + 256];
    const float bin = b_ih[col0 + 512];
    const float bhn = b_hh[col0 + 512];
    #pragma unroll
    for (int mt = 0; mt < 2; mt++) {
      #pragma unroll
      for (int v = 0; v < 4; v++) {
        const int m = rowBase + mt*16 + (quad << 2) + v;
        const size_t idx = (size_t)m * DIMN + col0;
        const float r_ = sigmoidf_(ar0[mt][v] + br);
        const float z_ = sigmoidf_(az0[mt][v] + bz);
        const float n_ = tanhf_(an0[mt][v] + bin + r_ * (ah0[mt][v] + bhn));
        OUT[idx] = (1.0f - z_) * n_ + z_ * H[idx];
      }
    }
  }
  {
    const float br  = b_ih[col1]       + b_hh[col1];
    const float bz  = b_ih[col1 + 256] + b_hh[col1 + 256];
    const float bin = b_ih[col1 + 512];
    const float bhn = b_hh[col1 + 512];
    #pragma unroll
    for (int mt = 0; mt < 2; mt++) {
      #pragma unroll
      for (int v = 0; v < 4; v++) {
        const int m = rowBase + mt*16 + (quad << 2) + v;
        const size_t idx = (size_t)m * DIMN + col1;
        const float r_ = sigmoidf_(ar1[mt][v] + br);
        const float z_ = sigmoidf_(az1[mt][v] + bz);
        const float n_ = tanhf_(an1[mt][v] + bin + r_ * (ah1[mt][v] + bhn));
        OUT[idx] = (1.0f - z_) * n_ + z_ * H[idx];
      }
    }
  }
}

// ---------------------------------------------------------------------------
extern "C" void kernel_launch(void* const* d_in, const int* in_sizes, int n_in,
                              void* d_out, int out_size, void* d_ws, size_t ws_size,
                              hipStream_t stream) {
  const float* x_obj  = (const float*)d_in[0];
  const float* x_pred = (const float*)d_in[1];
  const int*   pairs  = (const int*)d_in[2];
  const float* w_e2v  = (const float*)d_in[3];
  const float* b_e2v  = (const float*)d_in[4];
  const float* w_v2e  = (const float*)d_in[5];
  const float* b_v2e  = (const float*)d_in[6];
  const float* w_ih   = (const float*)d_in[7];
  const float* w_hh   = (const float*)d_in[8];
  const float* b_ih   = (const float*)d_in[9];
  const float* b_hh   = (const float*)d_in[10];

  char* ws = (char*)d_ws;
  size_t off = 0;
  float* msg = (float*)(ws + off); off += (size_t)NOBJ * DIMN * 4;     // 16 MB
  float* xg  = (float*)(ws + off); off += (size_t)NPAIR * DIMN * 4;    // 134 MB
  unsigned short* wbf = (unsigned short*)(ws + off); off += (size_t)2 * 768 * 256 * 2; // 786 KB
  float* gbuf = (float*)(ws + off); off += (size_t)NINC * 4;           // 1 MB
  int* row_start = (int*)(ws + off); off += (size_t)(NOBJ + 2) * 4;
  int* entries   = (int*)(ws + off); off += (size_t)NINC * 4;          // 1 MB
  // cnt & cursor only live during CSR build -> alias into msg region
  int* cnt    = (int*)msg;
  int* cursor = (int*)msg + NOBJ;

  float* O = (float*)d_out;                 // objects section
  float* P = O + (size_t)NOBJ * DIMN;       // predicates section

  conv_w<<<192, 256, 0, stream>>>(w_ih, w_hh, wbf);

  // CSR build (pairs are launch-constant; rebuilt every call for graph safety)
  (void)hipMemsetAsync(cnt, 0, NOBJ * sizeof(int), stream);
  hist_kernel<<<NINC / 256, 256, 0, stream>>>(pairs, cnt);
  scan_kernel<<<1, 1024, 0, stream>>>(cnt, row_start, cursor);
  scatter_kernel<<<NINC / 256, 256, 0, stream>>>(pairs, cursor, entries);

  const float* xo_cur = x_obj;
  const float* xp_cur = x_pred;
  for (int s = 0; s < 2; s++) {
    gate_kernel<<<NPAIR / 4, 256, 0, stream>>>(xo_cur, xp_cur, pairs,
                                               w_e2v, b_e2v, w_v2e, b_v2e, gbuf, xg);
    gather_kernel<<<NOBJ / 4, 256, 0, stream>>>(xp_cur, gbuf, row_start, entries, msg);
    gru_kernel<<<NOBJ / 32, 512, 0, stream>>>(msg, xo_cur, wbf, b_ih, b_hh, O);
    gru_kernel<<<NPAIR / 32, 512, 0, stream>>>(xg, xp_cur, wbf, b_ih, b_hh, P);
    xo_cur = O; xp_cur = P;
  }
}

// Round 6
// 859.979 us; speedup vs baseline: 1.3901x; 1.3901x over previous
//
#include <hip/hip_runtime.h>
#include <hip/hip_bf16.h>

#define DIMN  256
#define NOBJ  16384
#define NPAIR 131072
#define NINC  (2 * NPAIR)

typedef float  floatx4 __attribute__((ext_vector_type(4)));
typedef __bf16 bf16x8  __attribute__((ext_vector_type(8)));
typedef unsigned int u32;

static __device__ __forceinline__ unsigned f2bf(float f) {
  unsigned u = __builtin_bit_cast(unsigned, f);
  u += 0x7FFFu + ((u >> 16) & 1u);          // round-to-nearest-even
  return u >> 16;
}
static __device__ __forceinline__ float sigmoidf_(float x) {
  return 1.0f / (1.0f + __expf(-x));
}
static __device__ __forceinline__ float tanhf_(float x) {
  return 1.0f - 2.0f / (1.0f + __expf(2.0f * x));
}
static __device__ __forceinline__ float dot4(float4 a, float4 b) {
  return a.x*b.x + a.y*b.y + a.z*b.z + a.w*b.w;
}
static __device__ __forceinline__ float4 relu4(float4 a) {
  float4 r; r.x = fmaxf(a.x,0.f); r.y = fmaxf(a.y,0.f);
  r.z = fmaxf(a.z,0.f); r.w = fmaxf(a.w,0.f); return r;
}
static __device__ __forceinline__ floatx4 mfma16(bf16x8 a, bf16x8 b, floatx4 c) {
  return __builtin_amdgcn_mfma_f32_16x16x32_bf16(a, b, c, 0, 0, 0);
}
// fp32x8 -> bf16x8 via scalar casts; compiler emits v_cvt_pk_bf16_f32 pairs
// (RNE, numerically identical to f2bf; verified by unchanged absmax in v6).
static __device__ __forceinline__ bf16x8 cvt8(float4 u, float4 v) {
  bf16x8 r;
  r[0] = (__bf16)u.x; r[1] = (__bf16)u.y; r[2] = (__bf16)u.z; r[3] = (__bf16)u.w;
  r[4] = (__bf16)v.x; r[5] = (__bf16)v.y; r[6] = (__bf16)v.z; r[7] = (__bf16)v.w;
  return r;
}
// async global->LDS, 16 B per lane: LDS dest = uniform base + lane*16 (linear),
// global src = per-lane. Counted in vmcnt; __syncthreads() drains it.
typedef const __attribute__((address_space(1))) u32* gas_ptr;
typedef __attribute__((address_space(3))) u32*       las_ptr;
static __device__ __forceinline__ void gload16(const void* g, void* l) {
  __builtin_amdgcn_global_load_lds((gas_ptr)g, (las_ptr)l, 16, 0, 0);
}

// ---------------------------------------------------------------------------
// weight fp32 -> bf16, repacked into per-col-tile MFMA fragment order:
//   frag index i = ((ct*6 + s)*8 + kc)*64 + lane      (49152 frags of 16 B)
//   ct = col-tile of 16, s = stream (0..2 Wih r/z/n, 3..5 Whh r/z/n),
//   kc = K-chunk of 32, lane = (quad,l16): col = ct*16+l16, k0 = kc*32+quad*8.
__global__ __launch_bounds__(256) void conv_w(const float* __restrict__ wih,
                                              const float* __restrict__ whh,
                                              unsigned short* __restrict__ out) {
  const int i    = blockIdx.x * 256 + threadIdx.x;   // 0..49151
  const int lane = i & 63;
  const int kc   = (i >> 6) & 7;
  const int sct  = i >> 9;           // ct*6 + s
  const int s    = sct % 6;
  const int ct   = sct / 6;
  const int col  = ct * 16 + (lane & 15);
  const int k0   = kc * 32 + (lane >> 4) * 8;
  const float* src = (s < 3) ? (wih + ((size_t)(s * 256 + col)) * 256 + k0)
                             : (whh + ((size_t)((s - 3) * 256 + col)) * 256 + k0);
  float4 a = ((const float4*)src)[0];
  float4 b = ((const float4*)src)[1];
  uint4 pk;
  pk.x = f2bf(a.x) | (f2bf(a.y) << 16);
  pk.y = f2bf(a.z) | (f2bf(a.w) << 16);
  pk.z = f2bf(b.x) | (f2bf(b.y) << 16);
  pk.w = f2bf(b.z) | (f2bf(b.w) << 16);
  *(uint4*)(out + (size_t)i * 8) = pk;
}

// ---------------------------------------------------------------------------
// CSR build: histogram -> scan -> scatter. Incidence i (0..NINC): object
// pairs[i], pair p=i>>1, side i&1 (0=subj uses g_s, 1=obj uses g_o).
__global__ __launch_bounds__(256) void hist_kernel(const int* __restrict__ pairs,
                                                   int* __restrict__ cnt) {
  int i = blockIdx.x * 256 + threadIdx.x;
  atomicAdd(&cnt[pairs[i]], 1);
}

__global__ __launch_bounds__(1024) void scan_kernel(const int* __restrict__ cnt,
                                                    int* __restrict__ row_start,
                                                    int* __restrict__ cursor) {
  __shared__ int sums[1024];
  const int t = threadIdx.x;
  const int base = t * 16;
  int local[16];
  int s = 0;
  #pragma unroll
  for (int i = 0; i < 16; i++) { local[i] = s; s += cnt[base + i]; }
  sums[t] = s;
  __syncthreads();
  for (int off = 1; off < 1024; off <<= 1) {
    int v = (t >= off) ? sums[t - off] : 0;
    __syncthreads();
    sums[t] += v;
    __syncthreads();
  }
  const int prefix = (t == 0) ? 0 : sums[t - 1];
  #pragma unroll
  for (int i = 0; i < 16; i++) {
    int v = prefix + local[i];
    row_start[base + i] = v;
    cursor[base + i] = v;
  }
  if (t == 1023) row_start[16384] = sums[1023];
}

__global__ __launch_bounds__(256) void scatter_kernel(const int* __restrict__ pairs,
                                                      int* __restrict__ cursor,
                                                      int* __restrict__ entries) {
  int i = blockIdx.x * 256 + threadIdx.x;
  int pos = atomicAdd(&cursor[pairs[i]], 1);
  entries[pos] = i;
}

// ---------------------------------------------------------------------------
// Gate kernel: one wave per pair. Computes 4 gate scalars; writes
// xg = m_s2p + m_o2p as **bf16, pre-swizzled** for the GRU's LDS layout:
// 16B chunk c of row p lands at chunk position c ^ (p&7). Rounding point is
// identical to the old fp32-write + GRU-convert (one RNE after fp32 math).
__global__ __launch_bounds__(256) void gate_kernel(
    const float* __restrict__ xobj, const float* __restrict__ xpred,
    const int* __restrict__ pairs,
    const float* __restrict__ w_e2v, const float* __restrict__ b_e2v,
    const float* __restrict__ w_v2e, const float* __restrict__ b_v2e,
    float* __restrict__ gbuf, unsigned short* __restrict__ xg)
{
  const int wave = threadIdx.x >> 6;
  const int lane = threadIdx.x & 63;
  const int p = blockIdx.x * 4 + wave;
  const int s = pairs[2*p], o = pairs[2*p+1];

  float4 vp = ((const float4*)(xpred + (size_t)p*DIMN))[lane];
  float4 vs = ((const float4*)(xobj  + (size_t)s*DIMN))[lane];
  float4 vo = ((const float4*)(xobj  + (size_t)o*DIMN))[lane];
  float4 we0 = ((const float4*)w_e2v)[lane];
  float4 we1 = ((const float4*)w_e2v)[64 + lane];
  float4 wv0 = ((const float4*)w_v2e)[lane];
  float4 wv1 = ((const float4*)w_v2e)[64 + lane];

  float4 rp = relu4(vp), rs = relu4(vs), ro = relu4(vo);
  float t0 = dot4(rs, we0);
  float t1 = dot4(ro, we0);
  float t2 = dot4(rp, we1);
  float t3 = dot4(rp, wv0);
  float t4 = dot4(rs, wv1);
  float t5 = dot4(ro, wv1);
  #pragma unroll
  for (int off = 32; off >= 1; off >>= 1) {
    t0 += __shfl_xor(t0, off); t1 += __shfl_xor(t1, off);
    t2 += __shfl_xor(t2, off); t3 += __shfl_xor(t3, off);
    t4 += __shfl_xor(t4, off); t5 += __shfl_xor(t5, off);
  }
  const float be = b_e2v[0], bv = b_v2e[0];
  const float g_s  = sigmoidf_(t0 + t2 + be);
  const float g_o  = sigmoidf_(t1 + t2 + be);
  const float g_sp = sigmoidf_(t3 + t4 + bv);
  const float g_op = sigmoidf_(t3 + t5 + bv);

  // lane l owns bf16 elements [4l,4l+4) = half of 16B chunk (l>>1);
  // swizzled ushort offset = ((l>>1) ^ (p&7))*8 + (l&1)*4.
  ushort4 pk;
  pk.x = (unsigned short)f2bf(vs.x*g_sp + vo.x*g_op);
  pk.y = (unsigned short)f2bf(vs.y*g_sp + vo.y*g_op);
  pk.z = (unsigned short)f2bf(vs.z*g_sp + vo.z*g_op);
  pk.w = (unsigned short)f2bf(vs.w*g_sp + vo.w*g_op);
  unsigned short* xrow = xg + (size_t)p * DIMN;
  *(ushort4*)(xrow + ((lane >> 1) ^ (p & 7)) * 8 + (lane & 1) * 4) = pk;

  if (lane == 0) { gbuf[2*p] = g_s; gbuf[2*p+1] = g_o; }
}

// ---------------------------------------------------------------------------
// Gather segment-sum: one wave per object. Accumulates in fp32; writes msg
// as bf16, pre-swizzled (same layout rule as gate, keyed by obj&7).
__global__ __launch_bounds__(256) void gather_kernel(
    const float* __restrict__ xpred, const float* __restrict__ gbuf,
    const int* __restrict__ row_start, const int* __restrict__ entries,
    unsigned short* __restrict__ msg)
{
  const int wave = threadIdx.x >> 6;
  const int lane = threadIdx.x & 63;
  const int obj = blockIdx.x * 4 + wave;
  const int s0 = row_start[obj], s1 = row_start[obj + 1];

  float4 acc = {0.f, 0.f, 0.f, 0.f};
  int inc = (s0 < s1) ? entries[s0] : 0;
  for (int e = s0; e < s1; e++) {
    int ninc = (e + 1 < s1) ? entries[e + 1] : 0;   // prefetch next index
    float g = gbuf[inc];
    float4 v = ((const float4*)(xpred + (size_t)(inc >> 1) * DIMN))[lane];
    acc.x += g * v.x; acc.y += g * v.y; acc.z += g * v.z; acc.w += g * v.w;
    inc = ninc;
  }
  ushort4 pk;
  pk.x = (unsigned short)f2bf(acc.x);
  pk.y = (unsigned short)f2bf(acc.y);
  pk.z = (unsigned short)f2bf(acc.z);
  pk.w = (unsigned short)f2bf(acc.w);
  unsigned short* mrow = msg + (size_t)obj * DIMN;
  *(ushort4*)(mrow + ((lane >> 1) ^ (obj & 7)) * 8 + (lane & 1) * 4) = pk;
}

// ---------------------------------------------------------------------------
// Fused GRU v7 = v4 structure (64 rows x 256 cols, 16 waves, repacked-B,
// swizzled LDS) with X staging replaced by async global_load_lds:
//  - X arrives as bf16 ALREADY chunk-swizzled from gate/gather, so a linear
//    16B-per-lane copy (rule #21: linear dest + pre-swizzled source) yields
//    LDS contents byte-identical to v4's. Zero VGPRs, zero convert VALU.
//  - X loads issued FIRST; their HBM latency hides under H's fp32 load +
//    cvt + ds_write staging. One barrier drains both (vmcnt+lgkmcnt).
//  - H staging / K-loop / epilogue unchanged from v4 (known-good 200 us).
__global__ __launch_bounds__(1024) void gru_kernel(
    const unsigned short* __restrict__ Xbf, const float* __restrict__ H,
    const unsigned short* __restrict__ Wpk,
    const float* __restrict__ b_ih, const float* __restrict__ b_hh,
    float* __restrict__ OUT)
{
  __shared__ unsigned short Xs[64 * 256];
  __shared__ unsigned short Hs[64 * 256];

  const int tid  = threadIdx.x;
  const int lane = tid & 63;
  const int wave = tid >> 6;          // 0..15 -> col tile of 16
  const int quad = lane >> 4;
  const int l16  = lane & 15;
  const int rowBase = blockIdx.x * 64;
  const int col = wave * 16 + l16;

  // per-wave fragment base: frags at wb + s*4096 + kc*512 (ushort offsets)
  const unsigned short* wb = Wpk + (size_t)wave * 24576 + lane * 8;

  // ---- stage X: 32 async 16B-per-lane copies (each covers 2 rows of 512B).
  // wave w copies row pairs {2w, 2w+1} and {2w+32, 2w+33}.
  {
    const unsigned short* xsrc = Xbf + (size_t)rowBase * DIMN;
    const int R0 = wave * 2;
    gload16(xsrc + (size_t)R0 * DIMN + lane * 8,        Xs + R0 * DIMN);
    gload16(xsrc + (size_t)(R0 + 32) * DIMN + lane * 8, Xs + (R0 + 32) * DIMN);
  }

  // ---- stage H: 64 rows x 256 fp32 -> bf16 LDS (XOR-swizzled 16B chunks)
  {
    const int r  = tid >> 4;          // row 0..63
    const int c0 = tid & 15;          // chunk base; 16 threads per row
    const float* hr = H + (size_t)(rowBase + r) * DIMN;
    #pragma unroll
    for (int half = 0; half < 2; half++) {
      const int c  = c0 + half * 16;            // 16B chunk 0..31
      const int sw = (c ^ (r & 7)) * 8;         // swizzled ushort offset
      float4 u = ((const float4*)hr)[2*c];
      float4 v = ((const float4*)hr)[2*c + 1];
      *(bf16x8*)(Hs + r * 256 + sw) = cvt8(u, v);
    }
  }
  __syncthreads();

  floatx4 ar[4], az[4], an[4], ah[4];
  #pragma unroll
  for (int mt = 0; mt < 4; mt++) {
    ar[mt] = (floatx4){0,0,0,0}; az[mt] = (floatx4){0,0,0,0};
    an[mt] = (floatx4){0,0,0,0}; ah[mt] = (floatx4){0,0,0,0};
  }

  #pragma unroll
  for (int kc = 0; kc < 8; kc++) {
    const unsigned short* wk = wb + kc * 512;
    bf16x8 bri = *(const bf16x8*)(wk);
    bf16x8 bzi = *(const bf16x8*)(wk +  4096);
    bf16x8 bni = *(const bf16x8*)(wk +  8192);
    bf16x8 brh = *(const bf16x8*)(wk + 12288);
    bf16x8 bzh = *(const bf16x8*)(wk + 16384);
    bf16x8 bnh = *(const bf16x8*)(wk + 20480);
    #pragma unroll
    for (int mt = 0; mt < 4; mt++) {
      const int sw = ((kc * 4 + quad) ^ (l16 & 7)) * 8;   // row&7 == l16&7
      const int ao = (mt * 16 + l16) * 256 + sw;
      bf16x8 aX = *(const bf16x8*)(Xs + ao);
      bf16x8 aH = *(const bf16x8*)(Hs + ao);
      ar[mt] = mfma16(aX, bri, ar[mt]);
      ar[mt] = mfma16(aH, brh, ar[mt]);
      az[mt] = mfma16(aX, bzi, az[mt]);
      az[mt] = mfma16(aH, bzh, az[mt]);
      an[mt] = mfma16(aX, bni, an[mt]);
      ah[mt] = mfma16(aH, bnh, ah[mt]);
    }
  }

  // epilogue: C layout col=lane&15, row=quad*4+v (m89-verified)
  const float br  = b_ih[col]       + b_hh[col];
  const float bz  = b_ih[col + 256] + b_hh[col + 256];
  const float bin = b_ih[col + 512];
  const float bhn = b_hh[col + 512];
  #pragma unroll
  for (int mt = 0; mt < 4; mt++) {
    #pragma unroll
    for (int v = 0; v < 4; v++) {
      const int m = rowBase + mt*16 + (quad << 2) + v;
      const size_t idx = (size_t)m * DIMN + col;
      const float r_ = sigmoidf_(ar[mt][v] + br);
      const float z_ = sigmoidf_(az[mt][v] + bz);
      const float n_ = tanhf_(an[mt][v] + bin + r_ * (ah[mt][v] + bhn));
      OUT[idx] = (1.0f - z_) * n_ + z_ * H[idx];
    }
  }
}

// ---------------------------------------------------------------------------
extern "C" void kernel_launch(void* const* d_in, const int* in_sizes, int n_in,
                              void* d_out, int out_size, void* d_ws, size_t ws_size,
                              hipStream_t stream) {
  const float* x_obj  = (const float*)d_in[0];
  const float* x_pred = (const float*)d_in[1];
  const int*   pairs  = (const int*)d_in[2];
  const float* w_e2v  = (const float*)d_in[3];
  const float* b_e2v  = (const float*)d_in[4];
  const float* w_v2e  = (const float*)d_in[5];
  const float* b_v2e  = (const float*)d_in[6];
  const float* w_ih   = (const float*)d_in[7];
  const float* w_hh   = (const float*)d_in[8];
  const float* b_ih   = (const float*)d_in[9];
  const float* b_hh   = (const float*)d_in[10];

  char* ws = (char*)d_ws;
  size_t off = 0;
  unsigned short* msg = (unsigned short*)(ws + off); off += (size_t)NOBJ * DIMN * 2;   // 8.4 MB
  unsigned short* xg  = (unsigned short*)(ws + off); off += (size_t)NPAIR * DIMN * 2;  // 67 MB
  unsigned short* wbf = (unsigned short*)(ws + off); off += (size_t)2 * 768 * 256 * 2; // 786 KB
  float* gbuf = (float*)(ws + off); off += (size_t)NINC * 4;           // 1 MB
  int* row_start = (int*)(ws + off); off += (size_t)(NOBJ + 2) * 4;
  int* entries   = (int*)(ws + off); off += (size_t)NINC * 4;          // 1 MB
  // cnt & cursor only live during CSR build -> alias into msg region
  int* cnt    = (int*)msg;
  int* cursor = (int*)msg + NOBJ;

  float* O = (float*)d_out;                 // objects section
  float* P = O + (size_t)NOBJ * DIMN;       // predicates section

  conv_w<<<192, 256, 0, stream>>>(w_ih, w_hh, wbf);

  // CSR build (pairs are launch-constant; rebuilt every call for graph safety)
  (void)hipMemsetAsync(cnt, 0, NOBJ * sizeof(int), stream);
  hist_kernel<<<NINC / 256, 256, 0, stream>>>(pairs, cnt);
  scan_kernel<<<1, 1024, 0, stream>>>(cnt, row_start, cursor);
  scatter_kernel<<<NINC / 256, 256, 0, stream>>>(pairs, cursor, entries);

  const float* xo_cur = x_obj;
  const float* xp_cur = x_pred;
  for (int s = 0; s < 2; s++) {
    gate_kernel<<<NPAIR / 4, 256, 0, stream>>>(xo_cur, xp_cur, pairs,
                                               w_e2v, b_e2v, w_v2e, b_v2e, gbuf, xg);
    gather_kernel<<<NOBJ / 4, 256, 0, stream>>>(xp_cur, gbuf, row_start, entries, msg);
    gru_kernel<<<NOBJ / 64, 1024, 0, stream>>>(msg, xo_cur, wbf, b_ih, b_hh, O);
    gru_kernel<<<NPAIR / 64, 1024, 0, stream>>>(xg, xp_cur, wbf, b_ih, b_hh, P);
    xo_cur = O; xp_cur = P;
  }
}